// Round 6
// baseline (310.523 us; speedup 1.0000x reference)
//
#include <hip/hip_runtime.h>
#include <math.h>

#define ALPHA 0.12f
#define BETA  0.88f
#define OMEGA 6.0f
#define TWO_PI 6.28318530717958647692f

constexpr int Bn   = 4;
constexpr int Tn   = 4096;
constexpr int Dn   = 2048;
constexpr int HALF = Dn / 2;      // 1024
constexpr int L    = 16;          // chunk length (small => high occupancy)
constexpr int NC   = Tn / L;      // 256 chunks

typedef float fx4 __attribute__((ext_vector_type(4)));

constexpr float beta_pow(int n) {
    float r = 1.0f;
    for (int i = 0; i < n; ++i) r *= BETA;
    return r;
}
constexpr float BETA_L = beta_pow(L);   // beta^16

// ---------------------------------------------------------------------------
// Kernel 1: per-chunk local scan endpoint (zero init), fx4 lanes, EXACT.
//   S[b, c, d] = sum_{i=0..L-1} BETA^(L-1-i) * u[b, c*L+i, d]
// 524288 threads = 2048 blocks = 8 blocks/CU = 8 waves/SIMD.
// Pure stream: x read once (134 MB), S written once (8 MiB, regular stores
// so S stays L2/L3-resident for k2).
// ---------------------------------------------------------------------------
__global__ __launch_bounds__(256) void k_chunksum(
        const float* __restrict__ x,
        const float* __restrict__ input_scale,
        float* __restrict__ S) {
    int gid = blockIdx.x * blockDim.x + threadIdx.x;
    int d4 = gid & (Dn / 4 - 1);          // 0..511
    int c  = (gid >> 9) & (NC - 1);       // 0..255
    int b  = gid >> 17;                   // 0..3
    const float sc = ALPHA * (*input_scale);

    const fx4* xp = (const fx4*)(x + ((size_t)b * Tn + (size_t)c * L) * Dn) + d4;
    fx4 m = (fx4)(0.0f);
#pragma unroll
    for (int i = 0; i < L; ++i) {
        fx4 v = xp[(size_t)i * (Dn / 4)];
        m = BETA * m + sc * v;
    }
    ((fx4*)S)[gid] = m;   // gid*4 == b*NC*Dn + c*Dn + d4*4
}

// ---------------------------------------------------------------------------
// Kernel 2: final pass, EXACT. One block per (b, c); 256 fx4-pair threads.
// 1024 blocks = 4 blocks/CU = 4 waves/SIMD (4x round-3's k_final).
//  Prologue: exact carry-in E_{c-1} via prefix scan over S[b, 0..c-1, :]
//  (avg 128 coalesced iterations; loads independent, L2/L3-hit; only the
//  FMA chain is serial). Then the exact in-chunk recurrence, rotate,
//  residual. x re-read hits L3 (134 MB < 256 MiB, k1 just streamed it;
//  fills run before the iteration, not between kernels). Nontemporal
//  stores keep x/S resident in L3.
// ---------------------------------------------------------------------------
__global__ __launch_bounds__(256) void k_final(
        const float* __restrict__ x,
        const float* __restrict__ gate,
        const float* __restrict__ input_scale,
        const float* __restrict__ S,
        const float* __restrict__ mem_state,
        const int*   __restrict__ step_idx,
        float* __restrict__ out) {
    int p4 = threadIdx.x;                 // 0..255
    int c  = blockIdx.x & (NC - 1);       // 0..255
    int b  = blockIdx.x >> 8;             // 0..3

    const float sc  = ALPHA * (*input_scale);
    const float sig = 1.0f / (1.0f + expf(-(*gate)));

    // theta table for this chunk's 16 rows -> LDS (hidden under the scan)
    __shared__ float cs[L];
    __shared__ float ss[L];
    if (threadIdx.x < L) {
        int t = c * L + threadIdx.x;
        float tg = (float)(t + 1 + *step_idx);
        float theta = fmodf(OMEGA * log1pf(tg), TWO_PI);
        cs[threadIdx.x] = cosf(theta);
        ss[threadIdx.x] = sinf(theta);
    }

    // exact carry-in: ma/mb = E_{c-1}
    fx4 ma = ((const fx4*)mem_state)[p4];
    fx4 mb = ((const fx4*)mem_state)[p4 + HALF / 4];
    const fx4* Sa = (const fx4*)(S + (size_t)b * NC * Dn) + p4;
    const fx4* Sb = Sa + HALF / 4;
#pragma unroll 8
    for (int j = 0; j < c; ++j) {
        ma = BETA_L * ma + Sa[(size_t)j * (Dn / 4)];
        mb = BETA_L * mb + Sb[(size_t)j * (Dn / 4)];
    }
    __syncthreads();   // cs/ss ready (all 256 threads reach this)

    // output pass over chunk c (exact recurrence continued)
    size_t base = ((size_t)b * Tn + (size_t)c * L) * Dn;
    const fx4* xa = (const fx4*)(x + base) + p4;
    const fx4* xb = (const fx4*)(x + base + HALF) + p4;
    fx4* oa = (fx4*)(out + base) + p4;
    fx4* ob = (fx4*)(out + base + HALF) + p4;

#pragma unroll 8
    for (int i = 0; i < L; ++i) {
        fx4 va = xa[(size_t)i * (Dn / 4)];
        fx4 vb = xb[(size_t)i * (Dn / 4)];
        ma = BETA * ma + sc * va;
        mb = BETA * mb + sc * vb;
        float cth = cs[i];
        float sth = ss[i];
        fx4 ra = va + sig * (ma * cth - mb * sth);
        fx4 rb = vb + sig * (ma * sth + mb * cth);
        __builtin_nontemporal_store(ra, &oa[(size_t)i * (Dn / 4)]);
        __builtin_nontemporal_store(rb, &ob[(size_t)i * (Dn / 4)]);
    }
}

// ---------------------------------------------------------------------------
extern "C" void kernel_launch(void* const* d_in, const int* in_sizes, int n_in,
                              void* d_out, int out_size, void* d_ws, size_t ws_size,
                              hipStream_t stream) {
    const float* x           = (const float*)d_in[0];
    const float* gate        = (const float*)d_in[1];
    const float* input_scale = (const float*)d_in[2];
    const float* mem_state   = (const float*)d_in[3];
    const int*   step_idx    = (const int*)d_in[4];
    float* out = (float*)d_out;

    float* S = (float*)d_ws;   // Bn*NC*Dn floats = 8 MiB chunk sums

    k_chunksum<<<(Bn * NC * Dn / 4) / 256, 256, 0, stream>>>(x, input_scale, S);
    k_final<<<Bn * NC, 256, 0, stream>>>(x, gate, input_scale, S,
                                         mem_state, step_idx, out);
}

// Round 7
// 281.974 us; speedup vs baseline: 1.1012x; 1.1012x over previous
//
#include <hip/hip_runtime.h>
#include <math.h>

#define ALPHA 0.12f
#define BETA  0.88f
#define OMEGA 6.0f
#define TWO_PI 6.28318530717958647692f

constexpr int Bn   = 4;
constexpr int Tn   = 4096;
constexpr int Dn   = 2048;
constexpr int HALF = Dn / 2;      // 1024
constexpr int G    = 16;          // fine grain: output chunk & carry grain
constexpr int NQ   = Tn / G;      // 256 sub-chunks

typedef float fx4 __attribute__((ext_vector_type(4)));

constexpr float beta_pow(int n) {
    float r = 1.0f;
    for (int i = 0; i < n; ++i) r *= BETA;
    return r;
}
constexpr float BETA_G = beta_pow(G);   // beta^16

// ---------------------------------------------------------------------------
// Kernel 1: grain-16 local scan endpoints (zero init), fx4 lanes, EXACT.
//   S[b, q, d] = sum_{i=0..G-1} BETA^(G-1-i) * u[b, q*G+i, d]
// 524288 threads = 2048 blocks = 8 blocks/CU = 8 waves/SIMD. Pure coalesced
// stream: x read once (134 MB), S written once (8 MiB, regular stores so S
// stays cache-resident for k_carry).
// ---------------------------------------------------------------------------
__global__ __launch_bounds__(256) void k_sub(
        const float* __restrict__ x,
        const float* __restrict__ input_scale,
        float* __restrict__ S) {
    int gid = blockIdx.x * blockDim.x + threadIdx.x;
    int d4 = gid & (Dn / 4 - 1);          // 0..511
    int q  = (gid >> 9) & (NQ - 1);       // 0..255
    int b  = gid >> 17;                   // 0..3
    const float sc = ALPHA * (*input_scale);

    const fx4* xp = (const fx4*)(x + ((size_t)b * Tn + (size_t)q * G) * Dn) + d4;
    fx4 m = (fx4)(0.0f);
#pragma unroll
    for (int i = 0; i < G; ++i) {
        fx4 v = xp[(size_t)i * (Dn / 4)];
        m = BETA * m + sc * v;
    }
    ((fx4*)S)[gid] = m;   // gid*4 == b*NQ*Dn + q*Dn + d4*4
}

// ---------------------------------------------------------------------------
// Kernel 2: in-place convert S to carries, EXACT (round-0 k_mid trick).
// After this, S[b, q, :] = recurrence state ENTERING sub-chunk q.
// 8 blocks x 256 threads (one fx4 lane per (b, d4)). 256 iterations; only
// the 4-cycle FMA chain is serial — loads are address-independent and
// prefetchable, stores fire-and-forget. ~5 us.
//   m0 = mem_state;  loop q: s = S[q]; S[q] = m; m = beta^16 * m + s.
// ---------------------------------------------------------------------------
__global__ __launch_bounds__(256) void k_carry(
        float* __restrict__ S,
        const float* __restrict__ mem_state) {
    int gid = blockIdx.x * blockDim.x + threadIdx.x;   // 0..2047
    int d4 = gid & (Dn / 4 - 1);          // 0..511
    int b  = gid >> 9;                    // 0..3

    fx4 m = ((const fx4*)mem_state)[d4];
    fx4* Sp = (fx4*)S + (size_t)b * NQ * (Dn / 4) + d4;
    for (int q = 0; q < NQ; ++q) {
        fx4 s = Sp[(size_t)q * (Dn / 4)];
        Sp[(size_t)q * (Dn / 4)] = m;     // carry-in for sub-chunk q
        m = BETA_G * m + s;
    }
}
// ---------------------------------------------------------------------------
// Kernel 3: final pass, EXACT, no scan / no warm-up. One block per (b, q);
// 256 fx4-pair threads. 1024 blocks = 4 blocks/CU = 4 waves/SIMD.
// Work per block is the bare minimum: 1 carry load, 16-row stream of x
// (L3-hit — k_sub just streamed it; 134 MB < 256 MiB), rotate, residual,
// nontemporal store. Theta (16 rows) inline into LDS, hidden under loads.
// ---------------------------------------------------------------------------
__global__ __launch_bounds__(256) void k_final(
        const float* __restrict__ x,
        const float* __restrict__ gate,
        const float* __restrict__ input_scale,
        const float* __restrict__ S,      // now holds carries
        const int*   __restrict__ step_idx,
        float* __restrict__ out) {
    int p4 = threadIdx.x;                 // 0..255
    int q  = blockIdx.x & (NQ - 1);       // 0..255
    int b  = blockIdx.x >> 8;             // 0..3

    const float sc  = ALPHA * (*input_scale);
    const float sig = 1.0f / (1.0f + expf(-(*gate)));

    // theta table for this chunk's 16 rows -> LDS
    __shared__ float cs[G];
    __shared__ float ss[G];
    if (threadIdx.x < G) {
        int t = q * G + threadIdx.x;
        float tg = (float)(t + 1 + *step_idx);
        float theta = fmodf(OMEGA * log1pf(tg), TWO_PI);
        cs[threadIdx.x] = cosf(theta);
        ss[threadIdx.x] = sinf(theta);
    }

    // carry-in: state entering sub-chunk q (exact, precomputed)
    const fx4* Fp = (const fx4*)S + (size_t)(b * NQ + q) * (Dn / 4);
    fx4 ma = Fp[p4];
    fx4 mb = Fp[HALF / 4 + p4];
    __syncthreads();   // cs/ss ready (all 256 threads reach this)

    // output pass over sub-chunk q (exact recurrence continued)
    size_t base = ((size_t)b * Tn + (size_t)q * G) * Dn;
    const fx4* xa = (const fx4*)(x + base) + p4;
    const fx4* xb = (const fx4*)(x + base + HALF) + p4;
    fx4* oa = (fx4*)(out + base) + p4;
    fx4* ob = (fx4*)(out + base + HALF) + p4;

#pragma unroll
    for (int i = 0; i < G; ++i) {
        fx4 va = xa[(size_t)i * (Dn / 4)];
        fx4 vb = xb[(size_t)i * (Dn / 4)];
        ma = BETA * ma + sc * va;
        mb = BETA * mb + sc * vb;
        float cth = cs[i];
        float sth = ss[i];
        fx4 ra = va + sig * (ma * cth - mb * sth);
        fx4 rb = vb + sig * (ma * sth + mb * cth);
        __builtin_nontemporal_store(ra, &oa[(size_t)i * (Dn / 4)]);
        __builtin_nontemporal_store(rb, &ob[(size_t)i * (Dn / 4)]);
    }
}

// ---------------------------------------------------------------------------
extern "C" void kernel_launch(void* const* d_in, const int* in_sizes, int n_in,
                              void* d_out, int out_size, void* d_ws, size_t ws_size,
                              hipStream_t stream) {
    const float* x           = (const float*)d_in[0];
    const float* gate        = (const float*)d_in[1];
    const float* input_scale = (const float*)d_in[2];
    const float* mem_state   = (const float*)d_in[3];
    const int*   step_idx    = (const int*)d_in[4];
    float* out = (float*)d_out;

    float* S = (float*)d_ws;   // Bn*NQ*Dn floats = 8 MiB (sums, then carries)

    k_sub<<<(Bn * NQ * Dn / 4) / 256, 256, 0, stream>>>(x, input_scale, S);
    k_carry<<<(Bn * Dn / 4) / 256, 256, 0, stream>>>(S, mem_state);
    k_final<<<Bn * NQ, 256, 0, stream>>>(x, gate, input_scale, S,
                                         step_idx, out);
}

// Round 8
// 270.393 us; speedup vs baseline: 1.1484x; 1.0428x over previous
//
#include <hip/hip_runtime.h>
#include <math.h>

#define ALPHA 0.12f
#define BETA  0.88f
#define OMEGA 6.0f
#define TWO_PI 6.28318530717958647692f

constexpr int Bn   = 4;
constexpr int Tn   = 4096;
constexpr int Dn   = 2048;
constexpr int HALF = Dn / 2;      // 1024
constexpr int G    = 16;          // chunk grain
constexpr int NQ   = Tn / G;      // 256 chunks
constexpr int LB   = 6;           // lookback depth: beta^(16*6) = 4.7e-6

typedef float fx2 __attribute__((ext_vector_type(2)));
typedef float fx4 __attribute__((ext_vector_type(4)));

constexpr float beta_pow(int n) {
    float r = 1.0f;
    for (int i = 0; i < n; ++i) r *= BETA;
    return r;
}
constexpr float BETA_G = beta_pow(G);   // beta^16 = 0.129

// ---------------------------------------------------------------------------
// Kernel 1: grain-16 local scan endpoints (zero init), fx4 lanes, EXACT.
//   S[b, q, d] = sum_{i=0..G-1} BETA^(G-1-i) * u[b, q*G+i, d]
// 2048 blocks = 8 blocks/CU = 8 waves/SIMD. Pure coalesced stream:
// x read once (134 MB), S written once (8 MiB, regular stores -> L2-resident
// for k_final's lookback reads).
// ---------------------------------------------------------------------------
__global__ __launch_bounds__(256) void k_sub(
        const float* __restrict__ x,
        const float* __restrict__ input_scale,
        float* __restrict__ S) {
    int gid = blockIdx.x * blockDim.x + threadIdx.x;
    int d4 = gid & (Dn / 4 - 1);          // 0..511
    int q  = (gid >> 9) & (NQ - 1);       // 0..255
    int b  = gid >> 17;                   // 0..3
    const float sc = ALPHA * (*input_scale);

    const fx4* xp = (const fx4*)(x + ((size_t)b * Tn + (size_t)q * G) * Dn) + d4;
    fx4 m = (fx4)(0.0f);
#pragma unroll
    for (int i = 0; i < G; ++i) {
        fx4 v = xp[(size_t)i * (Dn / 4)];
        m = BETA * m + sc * v;
    }
    ((fx4*)S)[gid] = m;   // gid*4 == b*NQ*Dn + q*Dn + d4*4
}

// ---------------------------------------------------------------------------
// Kernel 2: final pass. NO serial kernel, NO per-block full scan.
// Carry-in via 6-deep truncated lookback over chunk sums:
//   E_q = sum_{j=q-6..q-1} beta^(16(q-1-j)) S_j   (+ exact m0 path for q<6)
// truncation error <= beta^96 ~ 4.7e-6 (60x tighter than rounds 4/5; absmax
// should stay at the exact-path 0.015625).
// Grid: Bn x NQ x 2 = 2048 blocks = 8 blocks/CU = 8 waves/SIMD; fx2 pair
// lanes, D-half split h. Regular stores (nt never exceeded 3.1 TB/s; fills
// at 6.7 TB/s use regular, and L3 doesn't retain x anyway per round 6).
// ---------------------------------------------------------------------------
__global__ __launch_bounds__(256) void k_final(
        const float* __restrict__ x,
        const float* __restrict__ gate,
        const float* __restrict__ input_scale,
        const float* __restrict__ S,
        const float* __restrict__ mem_state,
        const int*   __restrict__ step_idx,
        float* __restrict__ out) {
    int tid = threadIdx.x;                // 0..255
    int h   = blockIdx.x & 1;             // D-half split
    int q   = (blockIdx.x >> 1) & (NQ - 1);
    int b   = blockIdx.x >> 9;            // 0..3

    const float sc  = ALPHA * (*input_scale);
    const float sig = 1.0f / (1.0f + expf(-(*gate)));

    // theta table for this chunk's 16 rows -> LDS (hidden under lookback)
    __shared__ float cs[G];
    __shared__ float ss[G];
    if (tid < G) {
        int t = q * G + tid;
        float tg = (float)(t + 1 + *step_idx);
        float theta = fmodf(OMEGA * log1pf(tg), TWO_PI);
        cs[tid] = cosf(theta);
        ss[tid] = sinf(theta);
    }

    int k  = h * 256 + tid;               // pair-fx2 index 0..511
    int da = 2 * k;                       // float offset in a-half

    // carry-in: 6-deep lookback (exact for q<6 via m0)
    fx2 Ea, Eb;
    int j0 = q - LB;
    if (j0 < 0) {
        j0 = 0;
        Ea = *(const fx2*)(mem_state + da);
        Eb = *(const fx2*)(mem_state + HALF + da);
    } else {
        Ea = (fx2)(0.0f);
        Eb = (fx2)(0.0f);
    }
    const float* Sb_ = S + (size_t)b * NQ * Dn;
    for (int j = j0; j < q; ++j) {
        fx2 sa = *(const fx2*)(Sb_ + (size_t)j * Dn + da);
        fx2 sb = *(const fx2*)(Sb_ + (size_t)j * Dn + HALF + da);
        Ea = BETA_G * Ea + sa;
        Eb = BETA_G * Eb + sb;
    }
    __syncthreads();   // cs/ss ready (all 256 threads reach this)

    // output pass over chunk q (recurrence continued from carry-in)
    const float* xrow = x   + ((size_t)b * Tn + (size_t)q * G) * Dn;
    float*       orow = out + ((size_t)b * Tn + (size_t)q * G) * Dn;
#pragma unroll
    for (int i = 0; i < G; ++i) {
        fx2 va = *(const fx2*)(xrow + da);
        fx2 vb = *(const fx2*)(xrow + HALF + da);
        Ea = BETA * Ea + sc * va;
        Eb = BETA * Eb + sc * vb;
        float cth = cs[i];
        float sth = ss[i];
        fx2 ra = va + sig * (Ea * cth - Eb * sth);
        fx2 rb = vb + sig * (Ea * sth + Eb * cth);
        *(fx2*)(orow + da)        = ra;
        *(fx2*)(orow + HALF + da) = rb;
        xrow += Dn;
        orow += Dn;
    }
}

// ---------------------------------------------------------------------------
extern "C" void kernel_launch(void* const* d_in, const int* in_sizes, int n_in,
                              void* d_out, int out_size, void* d_ws, size_t ws_size,
                              hipStream_t stream) {
    const float* x           = (const float*)d_in[0];
    const float* gate        = (const float*)d_in[1];
    const float* input_scale = (const float*)d_in[2];
    const float* mem_state   = (const float*)d_in[3];
    const int*   step_idx    = (const int*)d_in[4];
    float* out = (float*)d_out;

    float* S = (float*)d_ws;   // Bn*NQ*Dn floats = 8 MiB chunk sums

    k_sub<<<(Bn * NQ * Dn / 4) / 256, 256, 0, stream>>>(x, input_scale, S);
    k_final<<<Bn * NQ * 2, 256, 0, stream>>>(x, gate, input_scale, S,
                                             mem_state, step_idx, out);
}